// Round 4
// baseline (542.646 us; speedup 1.0000x reference)
//
#include <hip/hip_runtime.h>
#include <hip/hip_bf16.h>
#include <stdint.h>

// MResConv on MI355X: two MeshCNN convs as bf16 MFMA GEMMs + fused BN stats.
// R3 (resubmit after infra timeout): 8-wave/512-thread blocks, 32-AGPR waves
// (64ch x 32e), single-buffer gather staging -> total regs <=128 -> 4 waves/SIMD.
// ws layout (bytes):
//   xT   [B][E][128] bf16      @ 0          (30,720,000)
//   Wf0  [20][256][32] bf16    @ 30720000   (327,680)
//   Wf1  [40][256][32] bf16    @ 31047680   (655,360)
//   x1   frag-blocked bf16     @ 31703040   (61,472,768)
//   rT   [B][E][256] bf16      @ 93175808   (61,440,000)
//   part [1876][2][512] f32    @ 154615808  (7,684,096)
//   ss   [2][256] f32          @ 162299904  (2,048)
//   bias [256] f32             @ 162301952  (1,024)

#define BB 4
#define CIN 128
#define COUT 256
#define EE 30000
#define BN 64
#define NTILES 469          // ceil(30000/64)
#define BC 64
#define KCH 320             // 5*BC K-values per chunk
#define PITCH 344           // KCH + 24 shorts: 688B rows, 16B aligned, bank-spread
#define NBLK (NTILES * BB)  // 1876
#define GRID1 1880          // swizzled 1D grid for conv kernels

typedef __attribute__((ext_vector_type(8))) short bf16x8;
typedef __attribute__((ext_vector_type(4))) float f32x4;

static __device__ __forceinline__ float blo(unsigned u) {
    union { unsigned u; float f; } v; v.u = u << 16; return v.f;
}
static __device__ __forceinline__ float bhi(unsigned u) {
    union { unsigned u; float f; } v; v.u = u & 0xffff0000u; return v.f;
}
static __device__ __forceinline__ unsigned pk2(float lo, float hi) {
    __hip_bfloat162 h = __float22bfloat162_rn(float2{lo, hi});   // v_cvt_pk_bf16_f32
    union { __hip_bfloat162 h; unsigned u; } v; v.h = h; return v.u;
}
static __device__ __forceinline__ unsigned short bf1(float f) {
    __hip_bfloat16 h = __float2bfloat16(f);
    union { __hip_bfloat16 h; unsigned short u; } v; v.h = h; return v.u;
}

// ---------------- transpose + cast: x[B,C,E] f32 -> xT[B,E,C] bf16 ----------
__global__ __launch_bounds__(256) void k_transpose(const float* __restrict__ x,
                                                   unsigned short* __restrict__ xT) {
    __shared__ float tile[64][CIN + 1];
    const int t = threadIdx.x;
    const int e0 = blockIdx.x * 64;
    const int b = blockIdx.y;
    const int el = t & 63;
    const bool ok = (e0 + el) < EE;
    const float* xb = x + (size_t)b * CIN * EE;
#pragma unroll
    for (int cc = 0; cc < CIN / 4; ++cc) {
        const int c = cc * 4 + (t >> 6);
        tile[el][c] = ok ? xb[(size_t)c * EE + e0 + el] : 0.f;
    }
    __syncthreads();
    const int el2 = t >> 2, cq = t & 3;
    if (e0 + el2 < EE) {
        unsigned ov[16];
#pragma unroll
        for (int i = 0; i < 16; ++i)
            ov[i] = pk2(tile[el2][cq * 32 + 2 * i], tile[el2][cq * 32 + 2 * i + 1]);
        int4* dst = (int4*)(xT + ((size_t)b * EE + e0 + el2) * CIN + cq * 32);
#pragma unroll
        for (int j = 0; j < 4; ++j)
            dst[j] = make_int4((int)ov[4 * j], (int)ov[4 * j + 1], (int)ov[4 * j + 2], (int)ov[4 * j + 3]);
    }
}

// ------------- W repack: W[m][c][k] f32 -> Wf[G/32][m][G%32] bf16 -----------
// K-order: G = chunk*KCH + k*BC + (c - chunk*BC), chunk = c/BC
// ss != null: fold BN scale (k<3: sc_c, else |sc_c|)
__global__ __launch_bounds__(256) void k_wprep(const float* __restrict__ W,
                                               unsigned short* __restrict__ Wf,
                                               const float* __restrict__ ss,
                                               int C, int K) {
    const int id = blockIdx.x * 256 + threadIdx.x;
    if (id >= 256 * K) return;
    const int m = id / K;
    const int G = id % K;
    const int chunk = G / KCH;
    const int r = G % KCH;
    const int k = r / BC;
    const int c = chunk * BC + (r % BC);
    float val = W[((size_t)m * C + c) * 5 + k];
    if (ss) {
        const float sc = ss[c];
        val *= (k < 3) ? sc : fabsf(sc);
    }
    Wf[((size_t)(G / 32) * 256 + m) * 32 + (G % 32)] = bf1(val);
}

// -------------------------- BN stats finalize -------------------------------
__global__ __launch_bounds__(256) void k_stats(const float* __restrict__ partials,
                                               const float* __restrict__ gamma,
                                               const float* __restrict__ beta,
                                               float* __restrict__ ss) {
    const int ch = blockIdx.x;
    const int t = threadIdx.x;
    float s = 0.f, q = 0.f;
    for (int i = t; i < NBLK * 2; i += 256) {
        s += partials[(size_t)i * 512 + ch];
        q += partials[(size_t)i * 512 + 256 + ch];
    }
    __shared__ float ls[256], lq[256];
    ls[t] = s; lq[t] = q;
    __syncthreads();
    for (int off = 128; off > 0; off >>= 1) {
        if (t < off) { ls[t] += ls[t + off]; lq[t] += lq[t + off]; }
        __syncthreads();
    }
    if (t == 0) {
        const float inv = 1.f / (float)(BB * EE);
        const float mean = ls[0] * inv;
        const float var = lq[0] * inv - mean * mean;
        const float sc = gamma[ch] * rsqrtf(var + 1e-5f);
        ss[ch] = sc;
        ss[COUT + ch] = beta[ch] - mean * sc;
    }
}

// ---------------- bias[o] = sum_c sh_c * (W1[o,c,0] + 2W1[o,c,1] + 2W1[o,c,2])
__global__ __launch_bounds__(256) void k_bias(const float* __restrict__ W1,
                                              const float* __restrict__ ss,
                                              float* __restrict__ bias) {
    const int o = blockIdx.x, t = threadIdx.x;
    const float sh = ss[COUT + t];
    const float* wr = W1 + ((size_t)o * COUT + t) * 5;
    float v = sh * (wr[0] + 2.f * (wr[1] + wr[2]));
    __shared__ float red[256];
    red[t] = v;
    __syncthreads();
    for (int off = 128; off > 0; off >>= 1) {
        if (t < off) red[t] += red[t + off];
        __syncthreads();
    }
    if (t == 0) bias[o] = red[0];
}

// --------------------------- fused mesh-conv GEMM ---------------------------
// 512 threads = 8 waves; block tile 256ch x 64e; wave tile 64ch x 32e.
// wch = w&3 (channel group), weh = w>>2 (e half). acc = 4x2 16x16 frags (32 rg).
// IS1=0: conv0 (writes x1 frag-blocked, rT=relu(x1), stat partials)
// IS1=1: conv1 (gathers raw rT; affine pre-folded into Wf/bias; adds x1, relu)
template <int C, int CHUNKS, int IS1>
__global__ __launch_bounds__(512, 4) void k_conv(
    const unsigned short* __restrict__ xin,
    const int* __restrict__ gmm,
    const unsigned short* __restrict__ Wf,
    const float* __restrict__ bias,
    unsigned short* __restrict__ x1,
    unsigned short* __restrict__ rT,
    float* __restrict__ partials,
    float* __restrict__ out) {
    __shared__ unsigned short f_lds[64 * PITCH];
    const int t = threadIdx.x;
    const int w = t >> 6, lane = t & 63;
    const int ml = lane & 15, g = lane >> 4;
    const int wch = w & 3, weh = w >> 2;
    // XCD batch-affinity decode: batch b -> XCDs {2b,2b+1}
    const int i = blockIdx.x;
    const int b = (i & 7) >> 1;
    const int tile = ((i >> 3) << 1) | (i & 1);
    if (tile >= NTILES) return;
    const int e0 = tile * BN;

    // build roles: 8 threads per edge, each owns 8 channels of each chunk
    const int be = t >> 3, bq = t & 7;
    const int eb = e0 + be;
    const int ec = (eb < EE) ? eb : 0;
    const int4 nb = *(const int4*)(gmm + ((size_t)b * EE + ec) * 4);

    const unsigned short* xb = xin + (size_t)b * EE * C;
    const unsigned short* rowc = xb + (size_t)ec * C;
    const unsigned short* row1 = xb + (size_t)nb.x * C;
    const unsigned short* row2 = xb + (size_t)nb.y * C;
    const unsigned short* row3 = xb + (size_t)nb.z * C;
    const unsigned short* row4 = xb + (size_t)nb.w * C;

    f32x4 acc[4][2];
#pragma unroll
    for (int ii = 0; ii < 4; ++ii)
#pragma unroll
        for (int jj = 0; jj < 2; ++jj)
            acc[ii][jj] = (f32x4){0.f, 0.f, 0.f, 0.f};

    int4 buf[5];   // single staging buffer: rows {1,3,2,4,c}, 16B each

    auto stage = [&](int chunk) {
        const int cb = chunk * BC + bq * 8;
        buf[0] = *(const int4*)(row1 + cb);
        buf[1] = *(const int4*)(row3 + cb);
        buf[2] = *(const int4*)(row2 + cb);
        buf[3] = *(const int4*)(row4 + cb);
        buf[4] = *(const int4*)(rowc + cb);
    };

    stage(0);
#pragma unroll 1
    for (int chunk = 0; chunk < CHUNKS; ++chunk) {
        // ---- build symmetric features from buf (registers only) ----
        const unsigned* r1 = (const unsigned*)&buf[0];
        const unsigned* r3 = (const unsigned*)&buf[1];
        const unsigned* r2 = (const unsigned*)&buf[2];
        const unsigned* r4 = (const unsigned*)&buf[3];
        const int4 ctr = buf[4];
        unsigned o1[4], o2[4], o3[4], o4[4];
#pragma unroll
        for (int j = 0; j < 4; ++j) {
            const float a0 = blo(r1[j]), a1 = bhi(r1[j]);
            const float b0 = blo(r3[j]), b1 = bhi(r3[j]);
            o1[j] = pk2(a0 + b0, a1 + b1);
            o3[j] = pk2(fabsf(a0 - b0), fabsf(a1 - b1));
        }
#pragma unroll
        for (int j = 0; j < 4; ++j) {
            const float a0 = blo(r2[j]), a1 = bhi(r2[j]);
            const float b0 = blo(r4[j]), b1 = bhi(r4[j]);
            o2[j] = pk2(a0 + b0, a1 + b1);
            o4[j] = pk2(fabsf(a0 - b0), fabsf(a1 - b1));
        }

        __syncthreads();   // previous chunk's MFMA reads of f_lds done
        {
            unsigned short* bp = &f_lds[be * PITCH + bq * 8];
            *(int4*)(bp + 0 * BC) = ctr;
            *(int4*)(bp + 1 * BC) = make_int4((int)o1[0], (int)o1[1], (int)o1[2], (int)o1[3]);
            *(int4*)(bp + 2 * BC) = make_int4((int)o2[0], (int)o2[1], (int)o2[2], (int)o2[3]);
            *(int4*)(bp + 3 * BC) = make_int4((int)o3[0], (int)o3[1], (int)o3[2], (int)o3[3]);
            *(int4*)(bp + 4 * BC) = make_int4((int)o4[0], (int)o4[1], (int)o4[2], (int)o4[3]);
        }
        if (chunk + 1 < CHUNKS) stage(chunk + 1);   // covered by kk-loop below
        __syncthreads();

        const unsigned short* wp = Wf + (size_t)chunk * (KCH / 32) * COUT * 32;
#pragma unroll 2
        for (int kk = 0; kk < KCH / 32; ++kk) {
            union { int4 i; bf16x8 h; } af[4], bfr[2];
#pragma unroll
            for (int fm = 0; fm < 4; ++fm)
                af[fm].i = *(const int4*)(wp + ((size_t)kk * COUT + (wch * 64 + fm * 16 + ml)) * 32 + g * 8);
#pragma unroll
            for (int fn = 0; fn < 2; ++fn)
                bfr[fn].i = *(const int4*)&f_lds[(weh * 32 + fn * 16 + ml) * PITCH + kk * 32 + g * 8];
#pragma unroll
            for (int fm = 0; fm < 4; ++fm)
#pragma unroll
                for (int fn = 0; fn < 2; ++fn)
                    acc[fm][fn] = __builtin_amdgcn_mfma_f32_16x16x32_bf16(af[fm].h, bfr[fn].h, acc[fm][fn], 0, 0, 0);
        }
    }

    // ------------------------------ epilogue --------------------------------
    const size_t fragbase = (((size_t)(b * NTILES + tile)) * 8 + w) * 8;
    if (!IS1) {
        float ks[4][4], kq[4][4];
#pragma unroll
        for (int fm = 0; fm < 4; ++fm)
#pragma unroll
            for (int r = 0; r < 4; ++r) { ks[fm][r] = 0.f; kq[fm][r] = 0.f; }
#pragma unroll
        for (int fm = 0; fm < 4; ++fm) {
#pragma unroll
            for (int fn = 0; fn < 2; ++fn) {
                const int fi = fm * 2 + fn;
                uint2 pk;
                pk.x = pk2(acc[fm][fn][0], acc[fm][fn][1]);
                pk.y = pk2(acc[fm][fn][2], acc[fm][fn][3]);
                *(uint2*)(x1 + (fragbase + fi) * 256 + lane * 4) = pk;   // coalesced
                const int e = e0 + weh * 32 + fn * 16 + ml;
                float rv0 = fmaxf(acc[fm][fn][0], 0.f), rv1 = fmaxf(acc[fm][fn][1], 0.f);
                float rv2 = fmaxf(acc[fm][fn][2], 0.f), rv3 = fmaxf(acc[fm][fn][3], 0.f);
                if (e < EE) {
                    uint2 pr;
                    pr.x = pk2(rv0, rv1);
                    pr.y = pk2(rv2, rv3);
                    *(uint2*)(rT + ((size_t)b * EE + e) * COUT + wch * 64 + fm * 16 + g * 4) = pr;
                } else {
                    rv0 = rv1 = rv2 = rv3 = 0.f;
                }
                ks[fm][0] += rv0; kq[fm][0] += rv0 * rv0;
                ks[fm][1] += rv1; kq[fm][1] += rv1 * rv1;
                ks[fm][2] += rv2; kq[fm][2] += rv2 * rv2;
                ks[fm][3] += rv3; kq[fm][3] += rv3 * rv3;
            }
        }
        // reduce over the 16 ml-lanes (same channels per (w,g))
#pragma unroll
        for (int fm = 0; fm < 4; ++fm) {
#pragma unroll
            for (int r = 0; r < 4; ++r) {
#pragma unroll
                for (int m = 1; m < 16; m <<= 1) {
                    ks[fm][r] += __shfl_xor(ks[fm][r], m);
                    kq[fm][r] += __shfl_xor(kq[fm][r], m);
                }
            }
        }
        if (ml == 0) {
            float* pp = partials + ((size_t)(b * NTILES + tile) * 2 + weh) * 512;
#pragma unroll
            for (int fm = 0; fm < 4; ++fm) {
                const int ch = wch * 64 + fm * 16 + g * 4;
                *(float4*)(pp + ch)       = make_float4(ks[fm][0], ks[fm][1], ks[fm][2], ks[fm][3]);
                *(float4*)(pp + 256 + ch) = make_float4(kq[fm][0], kq[fm][1], kq[fm][2], kq[fm][3]);
            }
        }
    } else {
#pragma unroll
        for (int fm = 0; fm < 4; ++fm) {
            const int chb = wch * 64 + fm * 16 + g * 4;
            const float4 bv = *(const float4*)(bias + chb);
#pragma unroll
            for (int fn = 0; fn < 2; ++fn) {
                const int fi = fm * 2 + fn;
                const uint2 pk = *(const uint2*)(x1 + (fragbase + fi) * 256 + lane * 4);
                const int e = e0 + weh * 32 + fn * 16 + ml;
                if (e < EE) {
                    float* op = out + ((size_t)b * COUT + chb) * EE + e;
                    op[0]              = fmaxf(acc[fm][fn][0] + bv.x + blo(pk.x), 0.f);
                    op[(size_t)EE]     = fmaxf(acc[fm][fn][1] + bv.y + bhi(pk.x), 0.f);
                    op[(size_t)2 * EE] = fmaxf(acc[fm][fn][2] + bv.z + blo(pk.y), 0.f);
                    op[(size_t)3 * EE] = fmaxf(acc[fm][fn][3] + bv.w + bhi(pk.y), 0.f);
                }
            }
        }
    }
}

extern "C" void kernel_launch(void* const* d_in, const int* in_sizes, int n_in,
                              void* d_out, int out_size, void* d_ws, size_t ws_size,
                              hipStream_t stream) {
    const float* x = (const float*)d_in[0];
    const int* gmm = (const int*)d_in[1];
    const float* W0 = (const float*)d_in[2];
    const float* gamma = (const float*)d_in[3];
    const float* beta = (const float*)d_in[4];
    const float* W1 = (const float*)d_in[5];
    float* out = (float*)d_out;

    char* ws = (char*)d_ws;
    unsigned short* xT  = (unsigned short*)(ws);
    unsigned short* Wf0 = (unsigned short*)(ws + 30720000);
    unsigned short* Wf1 = (unsigned short*)(ws + 31047680);
    unsigned short* x1  = (unsigned short*)(ws + 31703040);
    unsigned short* rT  = (unsigned short*)(ws + 93175808);
    float* partials     = (float*)(ws + 154615808);
    float* ss           = (float*)(ws + 162299904);
    float* bias         = (float*)(ws + 162301952);

    k_transpose<<<dim3(NTILES, BB), 256, 0, stream>>>(x, xT);
    k_wprep<<<dim3(640), 256, 0, stream>>>(W0, Wf0, nullptr, CIN, 640);
    k_conv<CIN, 2, 0><<<dim3(GRID1), 512, 0, stream>>>(
        xT, gmm, Wf0, nullptr, x1, rT, partials, nullptr);
    k_stats<<<dim3(256), 256, 0, stream>>>(partials, gamma, beta, ss);
    k_bias<<<dim3(256), 256, 0, stream>>>(W1, ss, bias);
    k_wprep<<<dim3(1280), 256, 0, stream>>>(W1, Wf1, ss, COUT, 1280);
    k_conv<COUT, 4, 1><<<dim3(GRID1), 512, 0, stream>>>(
        rT, gmm, Wf1, bias, x1, nullptr, nullptr, out);
}

// Round 7
// 533.240 us; speedup vs baseline: 1.0176x; 1.0176x over previous
//
#include <hip/hip_runtime.h>
#include <hip/hip_bf16.h>
#include <stdint.h>

// MResConv on MI355X: two MeshCNN convs as bf16 MFMA GEMMs + fused BN stats.
// R4 (3rd submit; prior two runs failed on infra, not kernel): scratch-free
// rewrite. R1-R3 were scratch-latency-bound (VGPR_Count=56: address-taken
// local arrays + unions demoted staging/fragments to scratch -> every mem op
// a serialized ~300cy round trip). All local state is now named variables /
// named struct members; fragments load directly via typed pointer casts from
// global/LDS. Structure otherwise identical to R3.
// ws layout (bytes):
//   xT   [B][E][128] bf16      @ 0          (30,720,000)
//   Wf0  [20][256][32] bf16    @ 30720000   (327,680)
//   Wf1  [40][256][32] bf16    @ 31047680   (655,360)
//   x1   frag-blocked bf16     @ 31703040   (61,472,768)
//   rT   [B][E][256] bf16      @ 93175808   (61,440,000)
//   part [1876][2][512] f32    @ 154615808  (7,684,096)
//   ss   [2][256] f32          @ 162299904  (2,048)
//   bias [256] f32             @ 162301952  (1,024)

#define BB 4
#define CIN 128
#define COUT 256
#define EE 30000
#define BN 64
#define NTILES 469          // ceil(30000/64)
#define BC 64
#define KCH 320             // 5*BC K-values per chunk
#define PITCH 344           // KCH + 24 shorts: 688B rows, 16B aligned
#define NBLK (NTILES * BB)  // 1876
#define GRID1 1880          // swizzled 1D grid for conv kernels

typedef __attribute__((ext_vector_type(8))) short bf16x8;
typedef __attribute__((ext_vector_type(4))) float f32x4;

static __device__ __forceinline__ float blo(unsigned u) {
    union { unsigned u; float f; } v; v.u = u << 16; return v.f;
}
static __device__ __forceinline__ float bhi(unsigned u) {
    union { unsigned u; float f; } v; v.u = u & 0xffff0000u; return v.f;
}
static __device__ __forceinline__ unsigned pk2(float lo, float hi) {
    __hip_bfloat162 h = __float22bfloat162_rn(float2{lo, hi});   // v_cvt_pk_bf16_f32
    union { __hip_bfloat162 h; unsigned u; } v; v.h = h; return v.u;
}
static __device__ __forceinline__ unsigned short bf1(float f) {
    __hip_bfloat16 h = __float2bfloat16(f);
    union { __hip_bfloat16 h; unsigned short u; } v; v.h = h; return v.u;
}
static __device__ __forceinline__ f32x4 red16(f32x4 v) {
#pragma unroll
    for (int m = 1; m < 16; m <<= 1) {
        v[0] += __shfl_xor(v[0], m);
        v[1] += __shfl_xor(v[1], m);
        v[2] += __shfl_xor(v[2], m);
        v[3] += __shfl_xor(v[3], m);
    }
    return v;
}

// named-member staging block: SROA-friendly (no arrays, no address-taken)
struct SG { uint4 r1, r3, r2, r4, rc; };

// ---------------- transpose + cast: x[B,C,E] f32 -> xT[B,E,C] bf16 ----------
__global__ __launch_bounds__(256) void k_transpose(const float* __restrict__ x,
                                                   unsigned short* __restrict__ xT) {
    __shared__ float tile[64][CIN + 1];
    const int t = threadIdx.x;
    const int e0 = blockIdx.x * 64;
    const int b = blockIdx.y;
    const int el = t & 63;
    const bool ok = (e0 + el) < EE;
    const float* xb = x + (size_t)b * CIN * EE;
#pragma unroll
    for (int cc = 0; cc < CIN / 4; ++cc) {
        const int c = cc * 4 + (t >> 6);
        tile[el][c] = ok ? xb[(size_t)c * EE + e0 + el] : 0.f;
    }
    __syncthreads();
    const int el2 = t >> 2, cq = t & 3;
    if (e0 + el2 < EE) {
        unsigned short* dst = xT + ((size_t)b * EE + e0 + el2) * CIN + cq * 32;
#pragma unroll
        for (int j = 0; j < 4; ++j) {
            const unsigned v0 = pk2(tile[el2][cq * 32 + 8 * j + 0], tile[el2][cq * 32 + 8 * j + 1]);
            const unsigned v1 = pk2(tile[el2][cq * 32 + 8 * j + 2], tile[el2][cq * 32 + 8 * j + 3]);
            const unsigned v2 = pk2(tile[el2][cq * 32 + 8 * j + 4], tile[el2][cq * 32 + 8 * j + 5]);
            const unsigned v3 = pk2(tile[el2][cq * 32 + 8 * j + 6], tile[el2][cq * 32 + 8 * j + 7]);
            *(uint4*)(dst + 8 * j) = make_uint4(v0, v1, v2, v3);
        }
    }
}

// ------------- W repack: W[m][c][k] f32 -> Wf[G/32][m][G%32] bf16 -----------
// K-order: G = chunk*KCH + k*BC + (c - chunk*BC), chunk = c/BC
// ss != null: fold BN scale (k<3: sc_c, else |sc_c|)
__global__ __launch_bounds__(256) void k_wprep(const float* __restrict__ W,
                                               unsigned short* __restrict__ Wf,
                                               const float* __restrict__ ss,
                                               int C, int K) {
    const int id = blockIdx.x * 256 + threadIdx.x;
    if (id >= 256 * K) return;
    const int m = id / K;
    const int G = id % K;
    const int chunk = G / KCH;
    const int r = G % KCH;
    const int k = r / BC;
    const int c = chunk * BC + (r % BC);
    float val = W[((size_t)m * C + c) * 5 + k];
    if (ss) {
        const float sc = ss[c];
        val *= (k < 3) ? sc : fabsf(sc);
    }
    Wf[((size_t)(G / 32) * 256 + m) * 32 + (G % 32)] = bf1(val);
}

// -------------------------- BN stats finalize -------------------------------
__global__ __launch_bounds__(256) void k_stats(const float* __restrict__ partials,
                                               const float* __restrict__ gamma,
                                               const float* __restrict__ beta,
                                               float* __restrict__ ss) {
    const int ch = blockIdx.x;
    const int t = threadIdx.x;
    float s = 0.f, q = 0.f;
    for (int i = t; i < NBLK * 2; i += 256) {
        s += partials[(size_t)i * 512 + ch];
        q += partials[(size_t)i * 512 + 256 + ch];
    }
    __shared__ float ls[256], lq[256];
    ls[t] = s; lq[t] = q;
    __syncthreads();
    for (int off = 128; off > 0; off >>= 1) {
        if (t < off) { ls[t] += ls[t + off]; lq[t] += lq[t + off]; }
        __syncthreads();
    }
    if (t == 0) {
        const float inv = 1.f / (float)(BB * EE);
        const float mean = ls[0] * inv;
        const float var = lq[0] * inv - mean * mean;
        const float sc = gamma[ch] * rsqrtf(var + 1e-5f);
        ss[ch] = sc;
        ss[COUT + ch] = beta[ch] - mean * sc;
    }
}

// ---------------- bias[o] = sum_c sh_c * (W1[o,c,0] + 2W1[o,c,1] + 2W1[o,c,2])
__global__ __launch_bounds__(256) void k_bias(const float* __restrict__ W1,
                                              const float* __restrict__ ss,
                                              float* __restrict__ bias) {
    const int o = blockIdx.x, t = threadIdx.x;
    const float sh = ss[COUT + t];
    const float* wr = W1 + ((size_t)o * COUT + t) * 5;
    float v = sh * (wr[0] + 2.f * (wr[1] + wr[2]));
    __shared__ float red[256];
    red[t] = v;
    __syncthreads();
    for (int off = 128; off > 0; off >>= 1) {
        if (t < off) red[t] += red[t + off];
        __syncthreads();
    }
    if (t == 0) bias[o] = red[0];
}

// feature-pair build: sum & |diff| of two packed bf16 pairs
#define FPAIR(ua_, ub_, osum_, odif_) do {                                   \
    const float fa0_ = blo(ua_), fa1_ = bhi(ua_);                            \
    const float fb0_ = blo(ub_), fb1_ = bhi(ub_);                            \
    osum_ = pk2(fa0_ + fb0_, fa1_ + fb1_);                                   \
    odif_ = pk2(fabsf(fa0_ - fb0_), fabsf(fa1_ - fb1_));                     \
} while (0)

#define STAGE(chv_, s_) do {                                                 \
    const int cb_ = (chv_) * BC + bq * 8;                                    \
    s_.r1 = *(const uint4*)(row1 + cb_);                                     \
    s_.r3 = *(const uint4*)(row3 + cb_);                                     \
    s_.r2 = *(const uint4*)(row2 + cb_);                                     \
    s_.r4 = *(const uint4*)(row4 + cb_);                                     \
    s_.rc = *(const uint4*)(rowc + cb_);                                     \
} while (0)

// conv0 epilogue for one fm: store x1 frags, rT=relu, accumulate stats
#define EP0(fm_, cA_, cB_, ksv_, kqv_) do {                                  \
    uint2 pkA_; pkA_.x = pk2(cA_[0], cA_[1]); pkA_.y = pk2(cA_[2], cA_[3]);  \
    *(uint2*)(x1 + (fragbase + (fm_) * 2 + 0) * 256 + lane * 4) = pkA_;      \
    uint2 pkB_; pkB_.x = pk2(cB_[0], cB_[1]); pkB_.y = pk2(cB_[2], cB_[3]);  \
    *(uint2*)(x1 + (fragbase + (fm_) * 2 + 1) * 256 + lane * 4) = pkB_;      \
    float r0_ = fmaxf(cA_[0], 0.f), r1_ = fmaxf(cA_[1], 0.f);                \
    float r2_ = fmaxf(cA_[2], 0.f), r3_ = fmaxf(cA_[3], 0.f);                \
    if (eA < EE) {                                                           \
        uint2 pr_; pr_.x = pk2(r0_, r1_); pr_.y = pk2(r2_, r3_);             \
        *(uint2*)(rT + ((size_t)b * EE + eA) * COUT + wch * 64 + (fm_) * 16 + g * 4) = pr_; \
    } else { r0_ = r1_ = r2_ = r3_ = 0.f; }                                  \
    ksv_[0] += r0_; kqv_[0] += r0_ * r0_; ksv_[1] += r1_; kqv_[1] += r1_ * r1_; \
    ksv_[2] += r2_; kqv_[2] += r2_ * r2_; ksv_[3] += r3_; kqv_[3] += r3_ * r3_; \
    float s0_ = fmaxf(cB_[0], 0.f), s1_ = fmaxf(cB_[1], 0.f);                \
    float s2_ = fmaxf(cB_[2], 0.f), s3_ = fmaxf(cB_[3], 0.f);                \
    if (eB < EE) {                                                           \
        uint2 pr_; pr_.x = pk2(s0_, s1_); pr_.y = pk2(s2_, s3_);             \
        *(uint2*)(rT + ((size_t)b * EE + eB) * COUT + wch * 64 + (fm_) * 16 + g * 4) = pr_; \
    } else { s0_ = s1_ = s2_ = s3_ = 0.f; }                                  \
    ksv_[0] += s0_; kqv_[0] += s0_ * s0_; ksv_[1] += s1_; kqv_[1] += s1_ * s1_; \
    ksv_[2] += s2_; kqv_[2] += s2_ * s2_; ksv_[3] += s3_; kqv_[3] += s3_ * s3_; \
} while (0)

// conv1 epilogue for one fm: residual add + bias + relu, f32 out
#define EP1(fm_, cA_, cB_) do {                                              \
    const int chb_ = wch * 64 + (fm_) * 16 + g * 4;                          \
    const float4 bv_ = *(const float4*)(bias + chb_);                        \
    const uint2 pkA_ = *(const uint2*)(x1 + (fragbase + (fm_) * 2 + 0) * 256 + lane * 4); \
    const uint2 pkB_ = *(const uint2*)(x1 + (fragbase + (fm_) * 2 + 1) * 256 + lane * 4); \
    if (eA < EE) {                                                           \
        float* op_ = out + ((size_t)b * COUT + chb_) * EE + eA;              \
        op_[0]              = fmaxf(cA_[0] + bv_.x + blo(pkA_.x), 0.f);      \
        op_[EE]             = fmaxf(cA_[1] + bv_.y + bhi(pkA_.x), 0.f);      \
        op_[2 * (size_t)EE] = fmaxf(cA_[2] + bv_.z + blo(pkA_.y), 0.f);      \
        op_[3 * (size_t)EE] = fmaxf(cA_[3] + bv_.w + bhi(pkA_.y), 0.f);      \
    }                                                                        \
    if (eB < EE) {                                                           \
        float* op_ = out + ((size_t)b * COUT + chb_) * EE + eB;              \
        op_[0]              = fmaxf(cB_[0] + bv_.x + blo(pkB_.x), 0.f);      \
        op_[EE]             = fmaxf(cB_[1] + bv_.y + bhi(pkB_.x), 0.f);      \
        op_[2 * (size_t)EE] = fmaxf(cB_[2] + bv_.z + blo(pkB_.y), 0.f);      \
        op_[3 * (size_t)EE] = fmaxf(cB_[3] + bv_.w + bhi(pkB_.y), 0.f);      \
    }                                                                        \
} while (0)

// --------------------------- fused mesh-conv GEMM ---------------------------
// 512 threads = 8 waves; block tile 256ch x 64e; wave tile 64ch x 32e.
// wch = w&3 (out-channel group), weh = w>>2 (edge half).
template <int C, int CHUNKS, int IS1>
__global__ __launch_bounds__(512, 2) void k_conv(
    const unsigned short* __restrict__ xin,
    const int* __restrict__ gmm,
    const unsigned short* __restrict__ Wf,
    const float* __restrict__ bias,
    unsigned short* __restrict__ x1,
    unsigned short* __restrict__ rT,
    float* __restrict__ partials,
    float* __restrict__ out) {
    __shared__ unsigned short f_lds[64 * PITCH];
    const int t = threadIdx.x;
    const int w = t >> 6, lane = t & 63;
    const int ml = lane & 15, g = lane >> 4;
    const int wch = w & 3, weh = w >> 2;
    // XCD batch-affinity decode: batch b -> XCDs {2b,2b+1}
    const int i = blockIdx.x;
    const int b = (i & 7) >> 1;
    const int tile = ((i >> 3) << 1) | (i & 1);
    if (tile >= NTILES) return;
    const int e0 = tile * BN;

    // build roles: 8 threads per edge, each owns 8 channels of each chunk
    const int be = t >> 3, bq = t & 7;
    const int eb = e0 + be;
    const int ec = (eb < EE) ? eb : 0;
    const int4 nb = *(const int4*)(gmm + ((size_t)b * EE + ec) * 4);

    const unsigned short* xb = xin + (size_t)b * EE * C;
    const unsigned short* rowc = xb + (size_t)ec * C;
    const unsigned short* row1 = xb + (size_t)nb.x * C;
    const unsigned short* row2 = xb + (size_t)nb.y * C;
    const unsigned short* row3 = xb + (size_t)nb.z * C;
    const unsigned short* row4 = xb + (size_t)nb.w * C;

    f32x4 c00 = {0.f, 0.f, 0.f, 0.f}, c01 = {0.f, 0.f, 0.f, 0.f};
    f32x4 c10 = {0.f, 0.f, 0.f, 0.f}, c11 = {0.f, 0.f, 0.f, 0.f};
    f32x4 c20 = {0.f, 0.f, 0.f, 0.f}, c21 = {0.f, 0.f, 0.f, 0.f};
    f32x4 c30 = {0.f, 0.f, 0.f, 0.f}, c31 = {0.f, 0.f, 0.f, 0.f};

    SG s;
    STAGE(0, s);

    // per-thread invariant addresses
    unsigned short* bp = &f_lds[be * PITCH + bq * 8];
    const unsigned short* wl = Wf + (wch * 64 + ml) * 32 + g * 8;
    const unsigned short* bl0 = &f_lds[(weh * 32 + ml) * PITCH + g * 8];
    const unsigned short* bl1 = bl0 + 16 * PITCH;

#pragma unroll 1
    for (int chunk = 0; chunk < CHUNKS; ++chunk) {
        // ---- build symmetric features (named registers only) ----
        unsigned o1x, o1y, o1z, o1w, o3x, o3y, o3z, o3w;
        unsigned o2x, o2y, o2z, o2w, o4x, o4y, o4z, o4w;
        FPAIR(s.r1.x, s.r3.x, o1x, o3x);
        FPAIR(s.r1.y, s.r3.y, o1y, o3y);
        FPAIR(s.r1.z, s.r3.z, o1z, o3z);
        FPAIR(s.r1.w, s.r3.w, o1w, o3w);
        FPAIR(s.r2.x, s.r4.x, o2x, o4x);
        FPAIR(s.r2.y, s.r4.y, o2y, o4y);
        FPAIR(s.r2.z, s.r4.z, o2z, o4z);
        FPAIR(s.r2.w, s.r4.w, o2w, o4w);
        const uint4 ctr = s.rc;

        if (chunk + 1 < CHUNKS) STAGE(chunk + 1, s);   // prefetch next gathers

        __syncthreads();   // previous chunk's MFMA LDS reads done
        *(uint4*)(bp + 0 * BC) = ctr;
        *(uint4*)(bp + 1 * BC) = make_uint4(o1x, o1y, o1z, o1w);
        *(uint4*)(bp + 2 * BC) = make_uint4(o2x, o2y, o2z, o2w);
        *(uint4*)(bp + 3 * BC) = make_uint4(o3x, o3y, o3z, o3w);
        *(uint4*)(bp + 4 * BC) = make_uint4(o4x, o4y, o4z, o4w);
        __syncthreads();

        const unsigned short* wc = wl + (size_t)chunk * (KCH / 32) * COUT * 32;
#pragma unroll
        for (int kk = 0; kk < KCH / 32; ++kk) {
            const bf16x8 a0 = *(const bf16x8*)(wc + kk * COUT * 32 + 0 * 512);
            const bf16x8 a1 = *(const bf16x8*)(wc + kk * COUT * 32 + 1 * 512);
            const bf16x8 a2 = *(const bf16x8*)(wc + kk * COUT * 32 + 2 * 512);
            const bf16x8 a3 = *(const bf16x8*)(wc + kk * COUT * 32 + 3 * 512);
            const bf16x8 b0 = *(const bf16x8*)(bl0 + kk * 32);
            const bf16x8 b1 = *(const bf16x8*)(bl1 + kk * 32);
            c00 = __builtin_amdgcn_mfma_f32_16x16x32_bf16(a0, b0, c00, 0, 0, 0);
            c01 = __builtin_amdgcn_mfma_f32_16x16x32_bf16(a0, b1, c01, 0, 0, 0);
            c10 = __builtin_amdgcn_mfma_f32_16x16x32_bf16(a1, b0, c10, 0, 0, 0);
            c11 = __builtin_amdgcn_mfma_f32_16x16x32_bf16(a1, b1, c11, 0, 0, 0);
            c20 = __builtin_amdgcn_mfma_f32_16x16x32_bf16(a2, b0, c20, 0, 0, 0);
            c21 = __builtin_amdgcn_mfma_f32_16x16x32_bf16(a2, b1, c21, 0, 0, 0);
            c30 = __builtin_amdgcn_mfma_f32_16x16x32_bf16(a3, b0, c30, 0, 0, 0);
            c31 = __builtin_amdgcn_mfma_f32_16x16x32_bf16(a3, b1, c31, 0, 0, 0);
        }
    }

    // ------------------------------ epilogue --------------------------------
    const size_t fragbase = (((size_t)(b * NTILES + tile)) * 8 + w) * 8;
    const int eA = e0 + weh * 32 + ml;
    const int eB = eA + 16;
    if (!IS1) {
        f32x4 ks0 = {0,0,0,0}, ks1 = {0,0,0,0}, ks2 = {0,0,0,0}, ks3 = {0,0,0,0};
        f32x4 kq0 = {0,0,0,0}, kq1 = {0,0,0,0}, kq2 = {0,0,0,0}, kq3 = {0,0,0,0};
        EP0(0, c00, c01, ks0, kq0);
        EP0(1, c10, c11, ks1, kq1);
        EP0(2, c20, c21, ks2, kq2);
        EP0(3, c30, c31, ks3, kq3);
        ks0 = red16(ks0); kq0 = red16(kq0);
        ks1 = red16(ks1); kq1 = red16(kq1);
        ks2 = red16(ks2); kq2 = red16(kq2);
        ks3 = red16(ks3); kq3 = red16(kq3);
        if (ml == 0) {
            float* pp = partials + ((size_t)(b * NTILES + tile) * 2 + weh) * 512;
            const int chq = wch * 64 + g * 4;
            *(float4*)(pp + chq + 0)        = make_float4(ks0[0], ks0[1], ks0[2], ks0[3]);
            *(float4*)(pp + chq + 16)       = make_float4(ks1[0], ks1[1], ks1[2], ks1[3]);
            *(float4*)(pp + chq + 32)       = make_float4(ks2[0], ks2[1], ks2[2], ks2[3]);
            *(float4*)(pp + chq + 48)       = make_float4(ks3[0], ks3[1], ks3[2], ks3[3]);
            *(float4*)(pp + 256 + chq + 0)  = make_float4(kq0[0], kq0[1], kq0[2], kq0[3]);
            *(float4*)(pp + 256 + chq + 16) = make_float4(kq1[0], kq1[1], kq1[2], kq1[3]);
            *(float4*)(pp + 256 + chq + 32) = make_float4(kq2[0], kq2[1], kq2[2], kq2[3]);
            *(float4*)(pp + 256 + chq + 48) = make_float4(kq3[0], kq3[1], kq3[2], kq3[3]);
        }
    } else {
        EP1(0, c00, c01);
        EP1(1, c10, c11);
        EP1(2, c20, c21);
        EP1(3, c30, c31);
    }
}

extern "C" void kernel_launch(void* const* d_in, const int* in_sizes, int n_in,
                              void* d_out, int out_size, void* d_ws, size_t ws_size,
                              hipStream_t stream) {
    const float* x = (const float*)d_in[0];
    const int* gmm = (const int*)d_in[1];
    const float* W0 = (const float*)d_in[2];
    const float* gamma = (const float*)d_in[3];
    const float* beta = (const float*)d_in[4];
    const float* W1 = (const float*)d_in[5];
    float* out = (float*)d_out;

    char* ws = (char*)d_ws;
    unsigned short* xT  = (unsigned short*)(ws);
    unsigned short* Wf0 = (unsigned short*)(ws + 30720000);
    unsigned short* Wf1 = (unsigned short*)(ws + 31047680);
    unsigned short* x1  = (unsigned short*)(ws + 31703040);
    unsigned short* rT  = (unsigned short*)(ws + 93175808);
    float* partials     = (float*)(ws + 154615808);
    float* ss           = (float*)(ws + 162299904);
    float* bias         = (float*)(ws + 162301952);

    k_transpose<<<dim3(NTILES, BB), 256, 0, stream>>>(x, xT);
    k_wprep<<<dim3(640), 256, 0, stream>>>(W0, Wf0, nullptr, CIN, 640);
    k_conv<CIN, 2, 0><<<dim3(GRID1), 512, 0, stream>>>(
        xT, gmm, Wf0, nullptr, x1, rT, partials, nullptr);
    k_stats<<<dim3(256), 256, 0, stream>>>(partials, gamma, beta, ss);
    k_bias<<<dim3(256), 256, 0, stream>>>(W1, ss, bias);
    k_wprep<<<dim3(1280), 256, 0, stream>>>(W1, Wf1, ss, COUT, 1280);
    k_conv<COUT, 4, 1><<<dim3(GRID1), 512, 0, stream>>>(
        rT, gmm, Wf1, bias, x1, nullptr, nullptr, out);
}

// Round 8
// 425.137 us; speedup vs baseline: 1.2764x; 1.2543x over previous
//
#include <hip/hip_runtime.h>
#include <hip/hip_bf16.h>
#include <stdint.h>

// MResConv on MI355X: two MeshCNN convs as bf16 MFMA GEMMs + fused BN stats.
// R5: barrier-drain fix + W dedup + depth-3 W pipeline.
//  - STAGE(c+1) now issued AFTER the 2nd barrier (no random gather ever gets
//    drained by the compiler's vmcnt(0)-before-s_barrier; latency hides under
//    the whole kk MFMA phase).
//  - Wave tile 32ch x 64e: 8 distinct wch groups -> W loaded exactly once per
//    block (was 2x via weh duplication).
//  - kk-loop: fully unrolled, 3 rotating named W-slots preloaded ahead ->
//    counted vmcnt waits instead of serialized per-group vmcnt(0).
// ws layout (bytes):
//   xT   [B][E][128] bf16      @ 0          (30,720,000)
//   Wf0  [20][256][32] bf16    @ 30720000   (327,680)
//   Wf1  [40][256][32] bf16    @ 31047680   (655,360)
//   x1   frag-blocked bf16     @ 31703040   (61,472,768)
//   rT   [B][E][256] bf16      @ 93175808   (61,440,000)
//   part [1876][2][256] f32    @ 154615808  (3,842,048)
//   ss   [2][256] f32          @ 162299904  (2,048)
//   bias [256] f32             @ 162301952  (1,024)

#define BB 4
#define CIN 128
#define COUT 256
#define EE 30000
#define BN 64
#define NTILES 469          // ceil(30000/64)
#define BC 64
#define KCH 320             // 5*BC K-values per chunk
#define PITCH 344           // KCH + 24 shorts: 688B rows, 16B aligned
#define NBLK (NTILES * BB)  // 1876
#define GRID1 1880          // swizzled 1D grid for conv kernels

typedef __attribute__((ext_vector_type(8))) short bf16x8;
typedef __attribute__((ext_vector_type(4))) float f32x4;

static __device__ __forceinline__ float blo(unsigned u) {
    union { unsigned u; float f; } v; v.u = u << 16; return v.f;
}
static __device__ __forceinline__ float bhi(unsigned u) {
    union { unsigned u; float f; } v; v.u = u & 0xffff0000u; return v.f;
}
static __device__ __forceinline__ unsigned pk2(float lo, float hi) {
    __hip_bfloat162 h = __float22bfloat162_rn(float2{lo, hi});   // v_cvt_pk_bf16_f32
    union { __hip_bfloat162 h; unsigned u; } v; v.h = h; return v.u;
}
static __device__ __forceinline__ unsigned short bf1(float f) {
    __hip_bfloat16 h = __float2bfloat16(f);
    union { __hip_bfloat16 h; unsigned short u; } v; v.h = h; return v.u;
}
static __device__ __forceinline__ f32x4 red16(f32x4 v) {
#pragma unroll
    for (int m = 1; m < 16; m <<= 1) {
        v[0] += __shfl_xor(v[0], m);
        v[1] += __shfl_xor(v[1], m);
        v[2] += __shfl_xor(v[2], m);
        v[3] += __shfl_xor(v[3], m);
    }
    return v;
}

// named-member staging block: SROA-friendly (no arrays, no address-taken)
struct SG { uint4 r1, r3, r2, r4, rc; };

// ---------------- transpose + cast: x[B,C,E] f32 -> xT[B,E,C] bf16 ----------
__global__ __launch_bounds__(256) void k_transpose(const float* __restrict__ x,
                                                   unsigned short* __restrict__ xT) {
    __shared__ float tile[64][CIN + 1];
    const int t = threadIdx.x;
    const int e0 = blockIdx.x * 64;
    const int b = blockIdx.y;
    const int el = t & 63;
    const bool ok = (e0 + el) < EE;
    const float* xb = x + (size_t)b * CIN * EE;
#pragma unroll
    for (int cc = 0; cc < CIN / 4; ++cc) {
        const int c = cc * 4 + (t >> 6);
        tile[el][c] = ok ? xb[(size_t)c * EE + e0 + el] : 0.f;
    }
    __syncthreads();
    const int el2 = t >> 2, cq = t & 3;
    if (e0 + el2 < EE) {
        unsigned short* dst = xT + ((size_t)b * EE + e0 + el2) * CIN + cq * 32;
#pragma unroll
        for (int j = 0; j < 4; ++j) {
            const unsigned v0 = pk2(tile[el2][cq * 32 + 8 * j + 0], tile[el2][cq * 32 + 8 * j + 1]);
            const unsigned v1 = pk2(tile[el2][cq * 32 + 8 * j + 2], tile[el2][cq * 32 + 8 * j + 3]);
            const unsigned v2 = pk2(tile[el2][cq * 32 + 8 * j + 4], tile[el2][cq * 32 + 8 * j + 5]);
            const unsigned v3 = pk2(tile[el2][cq * 32 + 8 * j + 6], tile[el2][cq * 32 + 8 * j + 7]);
            *(uint4*)(dst + 8 * j) = make_uint4(v0, v1, v2, v3);
        }
    }
}

// ------------- W repack: W[m][c][k] f32 -> Wf[G/32][m][G%32] bf16 -----------
// K-order: G = chunk*KCH + k*BC + (c - chunk*BC), chunk = c/BC
// ss != null: fold BN scale (k<3: sc_c, else |sc_c|)
__global__ __launch_bounds__(256) void k_wprep(const float* __restrict__ W,
                                               unsigned short* __restrict__ Wf,
                                               const float* __restrict__ ss,
                                               int C, int K) {
    const int id = blockIdx.x * 256 + threadIdx.x;
    if (id >= 256 * K) return;
    const int m = id / K;
    const int G = id % K;
    const int chunk = G / KCH;
    const int r = G % KCH;
    const int k = r / BC;
    const int c = chunk * BC + (r % BC);
    float val = W[((size_t)m * C + c) * 5 + k];
    if (ss) {
        const float sc = ss[c];
        val *= (k < 3) ? sc : fabsf(sc);
    }
    Wf[((size_t)(G / 32) * 256 + m) * 32 + (G % 32)] = bf1(val);
}

// -------------------------- BN stats finalize -------------------------------
__global__ __launch_bounds__(256) void k_stats(const float* __restrict__ partials,
                                               const float* __restrict__ gamma,
                                               const float* __restrict__ beta,
                                               float* __restrict__ ss) {
    const int ch = blockIdx.x;
    const int t = threadIdx.x;
    float s = 0.f, q = 0.f;
    for (int i = t; i < NBLK; i += 256) {
        s += partials[(size_t)i * 512 + ch];
        q += partials[(size_t)i * 512 + 256 + ch];
    }
    __shared__ float ls[256], lq[256];
    ls[t] = s; lq[t] = q;
    __syncthreads();
    for (int off = 128; off > 0; off >>= 1) {
        if (t < off) { ls[t] += ls[t + off]; lq[t] += lq[t + off]; }
        __syncthreads();
    }
    if (t == 0) {
        const float inv = 1.f / (float)(BB * EE);
        const float mean = ls[0] * inv;
        const float var = lq[0] * inv - mean * mean;
        const float sc = gamma[ch] * rsqrtf(var + 1e-5f);
        ss[ch] = sc;
        ss[COUT + ch] = beta[ch] - mean * sc;
    }
}

// ---------------- bias[o] = sum_c sh_c * (W1[o,c,0] + 2W1[o,c,1] + 2W1[o,c,2])
__global__ __launch_bounds__(256) void k_bias(const float* __restrict__ W1,
                                              const float* __restrict__ ss,
                                              float* __restrict__ bias) {
    const int o = blockIdx.x, t = threadIdx.x;
    const float sh = ss[COUT + t];
    const float* wr = W1 + ((size_t)o * COUT + t) * 5;
    float v = sh * (wr[0] + 2.f * (wr[1] + wr[2]));
    __shared__ float red[256];
    red[t] = v;
    __syncthreads();
    for (int off = 128; off > 0; off >>= 1) {
        if (t < off) red[t] += red[t + off];
        __syncthreads();
    }
    if (t == 0) bias[o] = red[0];
}

// feature-pair build: sum & |diff| of two packed bf16 pairs
#define FPAIR(ua_, ub_, osum_, odif_) do {                                   \
    const float fa0_ = blo(ua_), fa1_ = bhi(ua_);                            \
    const float fb0_ = blo(ub_), fb1_ = bhi(ub_);                            \
    osum_ = pk2(fa0_ + fb0_, fa1_ + fb1_);                                   \
    odif_ = pk2(fabsf(fa0_ - fb0_), fabsf(fa1_ - fb1_));                     \
} while (0)

#define STAGE(chv_, s_) do {                                                 \
    const int cb_ = (chv_) * BC + bq * 8;                                    \
    s_.r1 = *(const uint4*)(row1 + cb_);                                     \
    s_.r3 = *(const uint4*)(row3 + cb_);                                     \
    s_.r2 = *(const uint4*)(row2 + cb_);                                     \
    s_.r4 = *(const uint4*)(row4 + cb_);                                     \
    s_.rc = *(const uint4*)(rowc + cb_);                                     \
} while (0)

// W-slot load: 2 a-frags (fm=0,1) for one kk into named slot regs
#define LDW(slot_, kk_) do {                                                 \
    wa##slot_##_0 = *(const bf16x8*)(wc + (kk_) * 8192);                     \
    wa##slot_##_1 = *(const bf16x8*)(wc + (kk_) * 8192 + 512);               \
} while (0)

// one kk step: 4 LDS b-frags, 8 MFMA
#define MMK(kk_, slot_) do {                                                 \
    const bf16x8 bf0_ = *(const bf16x8*)(blp + (kk_) * 32);                  \
    const bf16x8 bf1_ = *(const bf16x8*)(blp + 16 * PITCH + (kk_) * 32);     \
    const bf16x8 bf2_ = *(const bf16x8*)(blp + 32 * PITCH + (kk_) * 32);     \
    const bf16x8 bf3_ = *(const bf16x8*)(blp + 48 * PITCH + (kk_) * 32);     \
    a00 = __builtin_amdgcn_mfma_f32_16x16x32_bf16(wa##slot_##_0, bf0_, a00, 0, 0, 0); \
    a10 = __builtin_amdgcn_mfma_f32_16x16x32_bf16(wa##slot_##_1, bf0_, a10, 0, 0, 0); \
    a01 = __builtin_amdgcn_mfma_f32_16x16x32_bf16(wa##slot_##_0, bf1_, a01, 0, 0, 0); \
    a11 = __builtin_amdgcn_mfma_f32_16x16x32_bf16(wa##slot_##_1, bf1_, a11, 0, 0, 0); \
    a02 = __builtin_amdgcn_mfma_f32_16x16x32_bf16(wa##slot_##_0, bf2_, a02, 0, 0, 0); \
    a12 = __builtin_amdgcn_mfma_f32_16x16x32_bf16(wa##slot_##_1, bf2_, a12, 0, 0, 0); \
    a03 = __builtin_amdgcn_mfma_f32_16x16x32_bf16(wa##slot_##_0, bf3_, a03, 0, 0, 0); \
    a13 = __builtin_amdgcn_mfma_f32_16x16x32_bf16(wa##slot_##_1, bf3_, a13, 0, 0, 0); \
} while (0)

// conv0 epilogue, one fragment (fm_, fn_, acc cc_)
#define EP0One(fm_, fn_, cc_, ksv_, kqv_) do {                               \
    uint2 pk_; pk_.x = pk2(cc_[0], cc_[1]); pk_.y = pk2(cc_[2], cc_[3]);     \
    *(uint2*)(x1 + (fragbase + (fm_) * 4 + (fn_)) * 256 + lane * 4) = pk_;   \
    const int e_ = e0 + (fn_) * 16 + ml;                                     \
    float r0_ = fmaxf(cc_[0], 0.f), r1_ = fmaxf(cc_[1], 0.f);                \
    float r2_ = fmaxf(cc_[2], 0.f), r3_ = fmaxf(cc_[3], 0.f);                \
    if (e_ < EE) {                                                           \
        uint2 pr_; pr_.x = pk2(r0_, r1_); pr_.y = pk2(r2_, r3_);             \
        *(uint2*)(rT + ((size_t)b * EE + e_) * COUT + w * 32 + (fm_) * 16 + g * 4) = pr_; \
    } else { r0_ = r1_ = r2_ = r3_ = 0.f; }                                  \
    ksv_[0] += r0_; kqv_[0] += r0_ * r0_; ksv_[1] += r1_; kqv_[1] += r1_ * r1_; \
    ksv_[2] += r2_; kqv_[2] += r2_ * r2_; ksv_[3] += r3_; kqv_[3] += r3_ * r3_; \
} while (0)

// conv1 epilogue, one fragment: residual add + bias + relu, f32 out
#define EP1One(fm_, fn_, cc_, bv_) do {                                      \
    const uint2 pk_ = *(const uint2*)(x1 + (fragbase + (fm_) * 4 + (fn_)) * 256 + lane * 4); \
    const int e_ = e0 + (fn_) * 16 + ml;                                     \
    if (e_ < EE) {                                                           \
        float* op_ = out + ((size_t)b * COUT + (w * 32 + (fm_) * 16 + g * 4)) * EE + e_; \
        op_[0]              = fmaxf(cc_[0] + bv_.x + blo(pk_.x), 0.f);       \
        op_[EE]             = fmaxf(cc_[1] + bv_.y + bhi(pk_.x), 0.f);       \
        op_[2 * (size_t)EE] = fmaxf(cc_[2] + bv_.z + blo(pk_.y), 0.f);       \
        op_[3 * (size_t)EE] = fmaxf(cc_[3] + bv_.w + bhi(pk_.y), 0.f);       \
    }                                                                        \
} while (0)

// --------------------------- fused mesh-conv GEMM ---------------------------
// 512 threads = 8 waves; block tile 256ch x 64e; wave tile 32ch x 64e.
// w = wch (0..7, distinct channel groups -> W loaded once per block).
template <int C, int CHUNKS, int IS1>
__global__ __launch_bounds__(512, 2) void k_conv(
    const unsigned short* __restrict__ xin,
    const int* __restrict__ gmm,
    const unsigned short* __restrict__ Wf,
    const float* __restrict__ bias,
    unsigned short* __restrict__ x1,
    unsigned short* __restrict__ rT,
    float* __restrict__ partials,
    float* __restrict__ out) {
    __shared__ unsigned short f_lds[64 * PITCH];
    const int t = threadIdx.x;
    const int w = t >> 6, lane = t & 63;
    const int ml = lane & 15, g = lane >> 4;
    // XCD batch-affinity decode: batch b -> XCDs {2b,2b+1}
    const int i = blockIdx.x;
    const int b = (i & 7) >> 1;
    const int tile = ((i >> 3) << 1) | (i & 1);
    if (tile >= NTILES) return;
    const int e0 = tile * BN;

    // build roles: 8 threads per edge, each owns 8 channels of each chunk
    const int be = t >> 3, bq = t & 7;
    const int eb = e0 + be;
    const int ec = (eb < EE) ? eb : 0;
    const int4 nb = *(const int4*)(gmm + ((size_t)b * EE + ec) * 4);

    const unsigned short* xb = xin + (size_t)b * EE * C;
    const unsigned short* rowc = xb + (size_t)ec * C;
    const unsigned short* row1 = xb + (size_t)nb.x * C;
    const unsigned short* row2 = xb + (size_t)nb.y * C;
    const unsigned short* row3 = xb + (size_t)nb.z * C;
    const unsigned short* row4 = xb + (size_t)nb.w * C;

    f32x4 a00 = {0.f,0.f,0.f,0.f}, a01 = {0.f,0.f,0.f,0.f};
    f32x4 a02 = {0.f,0.f,0.f,0.f}, a03 = {0.f,0.f,0.f,0.f};
    f32x4 a10 = {0.f,0.f,0.f,0.f}, a11 = {0.f,0.f,0.f,0.f};
    f32x4 a12 = {0.f,0.f,0.f,0.f}, a13 = {0.f,0.f,0.f,0.f};

    SG s;
    STAGE(0, s);

    // per-thread invariant addresses
    unsigned short* bp = &f_lds[be * PITCH + bq * 8];
    const unsigned short* wl = Wf + (size_t)(w * 32 + ml) * 32 + g * 8;  // A row base
    const unsigned short* blp = &f_lds[ml * PITCH + g * 8];              // B row base

#pragma unroll 1
    for (int chunk = 0; chunk < CHUNKS; ++chunk) {
        // ---- build symmetric features (named registers only) ----
        unsigned o1x, o1y, o1z, o1w, o3x, o3y, o3z, o3w;
        unsigned o2x, o2y, o2z, o2w, o4x, o4y, o4z, o4w;
        FPAIR(s.r1.x, s.r3.x, o1x, o3x);
        FPAIR(s.r1.y, s.r3.y, o1y, o3y);
        FPAIR(s.r1.z, s.r3.z, o1z, o3z);
        FPAIR(s.r1.w, s.r3.w, o1w, o3w);
        FPAIR(s.r2.x, s.r4.x, o2x, o4x);
        FPAIR(s.r2.y, s.r4.y, o2y, o4y);
        FPAIR(s.r2.z, s.r4.z, o2z, o4z);
        FPAIR(s.r2.w, s.r4.w, o2w, o4w);
        const uint4 ctr = s.rc;

        __syncthreads();   // previous chunk's MFMA LDS reads done (vmcnt clean here)
        *(uint4*)(bp + 0 * BC) = ctr;
        *(uint4*)(bp + 1 * BC) = make_uint4(o1x, o1y, o1z, o1w);
        *(uint4*)(bp + 2 * BC) = make_uint4(o2x, o2y, o2z, o2w);
        *(uint4*)(bp + 3 * BC) = make_uint4(o3x, o3y, o3z, o3w);
        *(uint4*)(bp + 4 * BC) = make_uint4(o4x, o4y, o4z, o4w);
        __syncthreads();

        // ---- kk phase: depth-3 rotating W pipeline; gathers for chunk+1
        //      issued after the first 3 W preloads (never cross a barrier) ----
        const unsigned short* wc = wl + (size_t)chunk * 10 * 8192;
        bf16x8 wa0_0, wa0_1, wa1_0, wa1_1, wa2_0, wa2_1;
        LDW(0, 0); LDW(1, 1); LDW(2, 2);
        if (chunk + 1 < CHUNKS) STAGE(chunk + 1, s);
        MMK(0, 0); LDW(0, 3);
        MMK(1, 1); LDW(1, 4);
        MMK(2, 2); LDW(2, 5);
        MMK(3, 0); LDW(0, 6);
        MMK(4, 1); LDW(1, 7);
        MMK(5, 2); LDW(2, 8);
        MMK(6, 0); LDW(0, 9);
        MMK(7, 1);
        MMK(8, 2);
        MMK(9, 0);
    }

    // ------------------------------ epilogue --------------------------------
    const size_t fragbase = (((size_t)(b * NTILES + tile)) * 8 + w) * 8;
    if (!IS1) {
        f32x4 ks0 = {0,0,0,0}, kq0 = {0,0,0,0};
        f32x4 ks1 = {0,0,0,0}, kq1 = {0,0,0,0};
        EP0One(0, 0, a00, ks0, kq0);
        EP0One(0, 1, a01, ks0, kq0);
        EP0One(0, 2, a02, ks0, kq0);
        EP0One(0, 3, a03, ks0, kq0);
        EP0One(1, 0, a10, ks1, kq1);
        EP0One(1, 1, a11, ks1, kq1);
        EP0One(1, 2, a12, ks1, kq1);
        EP0One(1, 3, a13, ks1, kq1);
        ks0 = red16(ks0); kq0 = red16(kq0);
        ks1 = red16(ks1); kq1 = red16(kq1);
        if (ml == 0) {
            float* pp = partials + (size_t)(b * NTILES + tile) * 512;
            const int ch0 = w * 32 + g * 4;
            *(float4*)(pp + ch0)            = make_float4(ks0[0], ks0[1], ks0[2], ks0[3]);
            *(float4*)(pp + ch0 + 16)       = make_float4(ks1[0], ks1[1], ks1[2], ks1[3]);
            *(float4*)(pp + 256 + ch0)      = make_float4(kq0[0], kq0[1], kq0[2], kq0[3]);
            *(float4*)(pp + 256 + ch0 + 16) = make_float4(kq1[0], kq1[1], kq1[2], kq1[3]);
        }
    } else {
        const float4 bv0 = *(const float4*)(bias + w * 32 + g * 4);
        const float4 bv1 = *(const float4*)(bias + w * 32 + 16 + g * 4);
        EP1One(0, 0, a00, bv0);
        EP1One(0, 1, a01, bv0);
        EP1One(0, 2, a02, bv0);
        EP1One(0, 3, a03, bv0);
        EP1One(1, 0, a10, bv1);
        EP1One(1, 1, a11, bv1);
        EP1One(1, 2, a12, bv1);
        EP1One(1, 3, a13, bv1);
    }
}

extern "C" void kernel_launch(void* const* d_in, const int* in_sizes, int n_in,
                              void* d_out, int out_size, void* d_ws, size_t ws_size,
                              hipStream_t stream) {
    const float* x = (const float*)d_in[0];
    const int* gmm = (const int*)d_in[1];
    const float* W0 = (const float*)d_in[2];
    const float* gamma = (const float*)d_in[3];
    const float* beta = (const float*)d_in[4];
    const float* W1 = (const float*)d_in[5];
    float* out = (float*)d_out;

    char* ws = (char*)d_ws;
    unsigned short* xT  = (unsigned short*)(ws);
    unsigned short* Wf0 = (unsigned short*)(ws + 30720000);
    unsigned short* Wf1 = (unsigned short*)(ws + 31047680);
    unsigned short* x1  = (unsigned short*)(ws + 31703040);
    unsigned short* rT  = (unsigned short*)(ws + 93175808);
    float* partials     = (float*)(ws + 154615808);
    float* ss           = (float*)(ws + 162299904);
    float* bias         = (float*)(ws + 162301952);

    k_transpose<<<dim3(NTILES, BB), 256, 0, stream>>>(x, xT);
    k_wprep<<<dim3(640), 256, 0, stream>>>(W0, Wf0, nullptr, CIN, 640);
    k_conv<CIN, 2, 0><<<dim3(GRID1), 512, 0, stream>>>(
        xT, gmm, Wf0, nullptr, x1, rT, partials, nullptr);
    k_stats<<<dim3(256), 256, 0, stream>>>(partials, gamma, beta, ss);
    k_bias<<<dim3(256), 256, 0, stream>>>(W1, ss, bias);
    k_wprep<<<dim3(1280), 256, 0, stream>>>(W1, Wf1, ss, COUT, 1280);
    k_conv<COUT, 4, 1><<<dim3(GRID1), 512, 0, stream>>>(
        rT, gmm, Wf1, bias, x1, nullptr, nullptr, out);
}